// Round 6
// baseline (348.663 us; speedup 1.0000x reference)
//
#include <hip/hip_runtime.h>

#define T_TOK 512
#define HDIM 2048
#define NEXP 8
#define IDIM 4096

typedef float f32x4 __attribute__((ext_vector_type(4)));
typedef __bf16 bf16x8 __attribute__((ext_vector_type(8)));
typedef unsigned short ushort8 __attribute__((ext_vector_type(8)));

// fp32 -> bf16 round-to-nearest-even
static __device__ __forceinline__ unsigned short f2bf(float f) {
    unsigned int u = __float_as_uint(f);
    u = (u + 0x7fffu + ((u >> 16) & 1u)) >> 16;
    return (unsigned short)u;
}

static __device__ __forceinline__ bf16x8 cvt8(const f32x4 lo, const f32x4 hi) {
    bf16x8 r;
#pragma unroll
    for (int q = 0; q < 4; ++q) { r[q] = (__bf16)lo[q]; r[q + 4] = (__bf16)hi[q]; }
    return r;
}

// ---------------- routing ------------------------------------------------------
__global__ void k_route(const float* __restrict__ logits,
                        int* __restrict__ off, int* __restrict__ tok,
                        float* __restrict__ scale) {
    __shared__ int cnt[NEXP], cur[NEXP];
    const int t = threadIdx.x;
    if (t < NEXP) cnt[t] = 0;
    __syncthreads();
    float m = logits[t * NEXP];
    int a = 0;
#pragma unroll
    for (int j = 1; j < NEXP; ++j) {
        float v = logits[t * NEXP + j];
        if (v > m) { m = v; a = j; }
    }
    scale[t] = 1.f / (1.f + __expf(-m));
    atomicAdd(&cnt[a], 1);
    __syncthreads();
    if (t == 0) {
        int o = 0;
        for (int e = 0; e < NEXP; ++e) { off[e] = o; cur[e] = o; o += cnt[e]; }
        off[NEXP] = o;
    }
    __syncthreads();
    int r = atomicAdd(&cur[a], 1);
    tok[r] = t;
}

// ---------------- gather + scale + bf16 ---------------------------------------
__global__ void k_gather(const float* __restrict__ x, const int* __restrict__ tok,
                         const float* __restrict__ scale,
                         unsigned short* __restrict__ xs) {
    const int pos = blockIdx.x;
    const int t = tok[pos];
    const float s = scale[t];
    const int c = threadIdx.x * 8;
    const float4* src = (const float4*)(x + (size_t)t * HDIM + c);
    float4 v0 = src[0], v1 = src[1];
    ushort8 o;
    o[0] = f2bf(v0.x * s); o[1] = f2bf(v0.y * s);
    o[2] = f2bf(v0.z * s); o[3] = f2bf(v0.w * s);
    o[4] = f2bf(v1.x * s); o[5] = f2bf(v1.y * s);
    o[6] = f2bf(v1.z * s); o[7] = f2bf(v1.w * s);
    *(ushort8*)(xs + (size_t)pos * HDIM + c) = o;
}

// fragment-load macros (shared by both GEMMs)
#define LOADA(dst, OFF)                                                     \
    {                                                                       \
        _Pragma("unroll") for (int fm = 0; fm < 4; ++fm)                    \
            _Pragma("unroll") for (int kk = 0; kk < 2; ++kk)                \
                dst[fm][kk] = *(const bf16x8*)(pA[fm] + (OFF) + kk * 32);   \
    }

// ---------------- GEMM1: gate/up + SiLU — all-register, no LDS, no barriers ----
// grid 8 experts * 256 n-slices; 64-thr blocks (1 wave). Wave: M=64, N=16, both mats.
__global__ void __launch_bounds__(64, 2)
k_moe1(const unsigned short* __restrict__ xs,
       const float* __restrict__ w1,
       const float* __restrict__ w3,
       const int* __restrict__ off,
       unsigned short* __restrict__ hbuf) {
    const int l = threadIdx.x;
    const int e = blockIdx.x >> 8;
    const int n0 = (blockIdx.x & 255) * 16;
    const int lr = l & 15, lk = (l >> 4) * 8;
    const int pos_beg = off[e], pos_end = off[e + 1];
    const int NK = HDIM / 64;  // 32

    const float* pB1 = w1 + (size_t)e * IDIM * HDIM + (size_t)(n0 + lr) * HDIM + lk;
    const float* pB3 = w3 + (size_t)e * IDIM * HDIM + (size_t)(n0 + lr) * HDIM + lk;

#define LOADB1(dG, dU, OFF)                                                 \
    {                                                                       \
        _Pragma("unroll") for (int kk = 0; kk < 2; ++kk) {                  \
            dG[kk][0] = *(const f32x4*)(b1 + (OFF) + kk * 32);              \
            dG[kk][1] = *(const f32x4*)(b1 + (OFF) + kk * 32 + 4);          \
            dU[kk][0] = *(const f32x4*)(b3 + (OFF) + kk * 32);              \
            dU[kk][1] = *(const f32x4*)(b3 + (OFF) + kk * 32 + 4);          \
        }                                                                   \
    }

#define COMPUTE1(a, G, U)                                                   \
    {                                                                       \
        _Pragma("unroll") for (int kk = 0; kk < 2; ++kk) {                  \
            bf16x8 bg = cvt8(G[kk][0], G[kk][1]);                           \
            bf16x8 bu = cvt8(U[kk][0], U[kk][1]);                           \
            _Pragma("unroll") for (int fm = 0; fm < 4; ++fm) {              \
                accG[fm] = __builtin_amdgcn_mfma_f32_16x16x32_bf16(         \
                    a[fm][kk], bg, accG[fm], 0, 0, 0);                      \
                accU[fm] = __builtin_amdgcn_mfma_f32_16x16x32_bf16(         \
                    a[fm][kk], bu, accU[fm], 0, 0, 0);                      \
            }                                                               \
        }                                                                   \
    }

    for (int m0 = pos_beg; m0 < pos_end; m0 += 64) {
        const unsigned short* pA[4];
#pragma unroll
        for (int fm = 0; fm < 4; ++fm) {
            int gr = m0 + fm * 16 + lr; if (gr > T_TOK - 1) gr = T_TOK - 1;
            pA[fm] = xs + (size_t)gr * HDIM + lk;
        }
        const float* b1 = pB1;
        const float* b3 = pB3;

        f32x4 accG[4], accU[4];
#pragma unroll
        for (int i = 0; i < 4; ++i) { accG[i] = (f32x4){0,0,0,0}; accU[i] = (f32x4){0,0,0,0}; }

        bf16x8 aA[4][2], aB[4][2];
        f32x4 gA[2][2], uA[2][2], gB[2][2], uB[2][2];

        LOADA(aA, 0) LOADB1(gA, uA, 0)
#pragma unroll 1
        for (int ks = 0; ks < NK; ks += 2) {
            LOADA(aB, 64) LOADB1(gB, uB, 64)      // set for step ks+1 (always valid)
            COMPUTE1(aA, gA, uA)
            if (ks + 2 < NK) { LOADA(aA, 128) LOADB1(gA, uA, 128) }
            COMPUTE1(aB, gB, uB)
#pragma unroll
            for (int fm = 0; fm < 4; ++fm) pA[fm] += 128;
            b1 += 128; b3 += 128;
        }

        // epilogue: h = silu(gate) * up -> bf16 (C layout: col=l&15, row=(l>>4)*4+r)
#pragma unroll
        for (int fm = 0; fm < 4; ++fm)
#pragma unroll
            for (int r = 0; r < 4; ++r) {
                const int pos = m0 + fm * 16 + (l >> 4) * 4 + r;
                if (pos < pos_end) {
                    const float gv = accG[fm][r];
                    const float uv = accU[fm][r];
                    const float hv = gv / (1.f + __expf(-gv)) * uv;
                    hbuf[(size_t)pos * IDIM + n0 + lr] = f2bf(hv);
                }
            }
    }
#undef LOADB1
#undef COMPUTE1
}

// ---------------- GEMM2: down proj + scatter — all-register ---------------------
// grid 8 experts * 128 n-slices; 64-thr blocks. Wave: M=64, N=16, K=4096.
__global__ void __launch_bounds__(64, 2)
k_moe2(const unsigned short* __restrict__ hbuf,
       const float* __restrict__ w2,
       const int* __restrict__ off,
       const int* __restrict__ tok,
       float* __restrict__ out) {
    const int l = threadIdx.x;
    const int e = blockIdx.x >> 7;
    const int n0 = (blockIdx.x & 127) * 16;
    const int lr = l & 15, lk = (l >> 4) * 8;
    const int pos_beg = off[e], pos_end = off[e + 1];
    const int NK = IDIM / 64;  // 64

    const float* pB2 = w2 + (size_t)e * HDIM * IDIM + (size_t)(n0 + lr) * IDIM + lk;

#define LOADB2(dB, OFF)                                                     \
    {                                                                       \
        _Pragma("unroll") for (int kk = 0; kk < 2; ++kk) {                  \
            dB[kk][0] = *(const f32x4*)(b2 + (OFF) + kk * 32);              \
            dB[kk][1] = *(const f32x4*)(b2 + (OFF) + kk * 32 + 4);          \
        }                                                                   \
    }

#define COMPUTE2(a, B)                                                      \
    {                                                                       \
        _Pragma("unroll") for (int kk = 0; kk < 2; ++kk) {                  \
            bf16x8 bb = cvt8(B[kk][0], B[kk][1]);                           \
            _Pragma("unroll") for (int fm = 0; fm < 4; ++fm)                \
                acc[fm] = __builtin_amdgcn_mfma_f32_16x16x32_bf16(          \
                    a[fm][kk], bb, acc[fm], 0, 0, 0);                       \
        }                                                                   \
    }

    for (int m0 = pos_beg; m0 < pos_end; m0 += 64) {
        const unsigned short* pA[4];
#pragma unroll
        for (int fm = 0; fm < 4; ++fm) {
            int gr = m0 + fm * 16 + lr; if (gr > T_TOK - 1) gr = T_TOK - 1;
            pA[fm] = hbuf + (size_t)gr * IDIM + lk;
        }
        const float* b2 = pB2;

        f32x4 acc[4];
#pragma unroll
        for (int i = 0; i < 4; ++i) acc[i] = (f32x4){0,0,0,0};

        bf16x8 aA[4][2], aB[4][2];
        f32x4 bA[2][2], bB[2][2];

        LOADA(aA, 0) LOADB2(bA, 0)
#pragma unroll 1
        for (int ks = 0; ks < NK; ks += 2) {
            LOADA(aB, 64) LOADB2(bB, 64)
            COMPUTE2(aA, bA)
            if (ks + 2 < NK) { LOADA(aA, 128) LOADB2(bA, 128) }
            COMPUTE2(aB, bB)
#pragma unroll
            for (int fm = 0; fm < 4; ++fm) pA[fm] += 128;
            b2 += 128;
        }

#pragma unroll
        for (int fm = 0; fm < 4; ++fm)
#pragma unroll
            for (int r = 0; r < 4; ++r) {
                const int pos = m0 + fm * 16 + (l >> 4) * 4 + r;
                if (pos < pos_end) {
                    const int t = tok[pos];
                    out[(size_t)t * HDIM + n0 + lr] = acc[fm][r];
                }
            }
    }
#undef LOADB2
#undef COMPUTE2
}

extern "C" void kernel_launch(void* const* d_in, const int* in_sizes, int n_in,
                              void* d_out, int out_size, void* d_ws, size_t ws_size,
                              hipStream_t stream) {
    const float* x      = (const float*)d_in[0];
    const float* logits = (const float*)d_in[1];
    const float* w1     = (const float*)d_in[2];
    const float* w3     = (const float*)d_in[3];
    const float* w2     = (const float*)d_in[4];
    float* out = (float*)d_out;

    char* ws = (char*)d_ws;
    int* off   = (int*)ws;                          // 9 ints
    int* tok   = (int*)(ws + 64);                   // 512 ints
    float* scl = (float*)(ws + 64 + 2048);          // 512 floats
    unsigned short* xs   = (unsigned short*)(ws + 8192);                             // 2 MiB
    unsigned short* hbuf = (unsigned short*)(ws + 8192 + (size_t)T_TOK * HDIM * 2);  // 4 MiB

    k_route<<<1, T_TOK, 0, stream>>>(logits, off, tok, scl);
    k_gather<<<T_TOK, 256, 0, stream>>>(x, tok, scl, xs);
    k_moe1<<<NEXP * (IDIM / 16), 64, 0, stream>>>(xs, w1, w3, off, hbuf);
    k_moe2<<<NEXP * (HDIM / 16), 64, 0, stream>>>(hbuf, w2, off, tok, out);
}

// Round 7
// 311.034 us; speedup vs baseline: 1.1210x; 1.1210x over previous
//
#include <hip/hip_runtime.h>

#define T_TOK 512
#define HDIM 2048
#define NEXP 8
#define IDIM 4096

typedef float f32x4 __attribute__((ext_vector_type(4)));
typedef __bf16 bf16x8 __attribute__((ext_vector_type(8)));
typedef unsigned short ushort8 __attribute__((ext_vector_type(8)));

// fp32 -> bf16 round-to-nearest-even
static __device__ __forceinline__ unsigned short f2bf(float f) {
    unsigned int u = __float_as_uint(f);
    u = (u + 0x7fffu + ((u >> 16) & 1u)) >> 16;
    return (unsigned short)u;
}

static __device__ __forceinline__ bf16x8 cvt8(const f32x4 lo, const f32x4 hi) {
    bf16x8 r;
#pragma unroll
    for (int q = 0; q < 4; ++q) { r[q] = (__bf16)lo[q]; r[q + 4] = (__bf16)hi[q]; }
    return r;
}

// async global->LDS, 16 B/lane; LDS dest = wave-uniform base + lane*16,
// global source is PER-LANE (used for the in-chunk XOR swizzle)
static __device__ __forceinline__ void gload_lds16(const void* g, void* l) {
    auto gp = reinterpret_cast<const unsigned int __attribute__((address_space(1)))*>(
        reinterpret_cast<unsigned long long>(g));
    auto lp = reinterpret_cast<unsigned int __attribute__((address_space(3)))*>(
        static_cast<unsigned int>(reinterpret_cast<unsigned long long>(l)));
    __builtin_amdgcn_global_load_lds(gp, lp, 16, 0, 0);
}

// ---------------- routing ------------------------------------------------------
__global__ void k_route(const float* __restrict__ logits,
                        int* __restrict__ off, int* __restrict__ tok,
                        float* __restrict__ scale) {
    __shared__ int cnt[NEXP], cur[NEXP];
    const int t = threadIdx.x;
    if (t < NEXP) cnt[t] = 0;
    __syncthreads();
    float m = logits[t * NEXP];
    int a = 0;
#pragma unroll
    for (int j = 1; j < NEXP; ++j) {
        float v = logits[t * NEXP + j];
        if (v > m) { m = v; a = j; }
    }
    scale[t] = 1.f / (1.f + __expf(-m));
    atomicAdd(&cnt[a], 1);
    __syncthreads();
    if (t == 0) {
        int o = 0;
        for (int e = 0; e < NEXP; ++e) { off[e] = o; cur[e] = o; o += cnt[e]; }
        off[NEXP] = o;
    }
    __syncthreads();
    int r = atomicAdd(&cur[a], 1);
    tok[r] = t;
}

// ---------------- gather + scale + bf16 ---------------------------------------
__global__ void k_gather(const float* __restrict__ x, const int* __restrict__ tok,
                         const float* __restrict__ scale,
                         unsigned short* __restrict__ xs) {
    const int pos = blockIdx.x;
    const int t = tok[pos];
    const float s = scale[t];
    const int c = threadIdx.x * 8;
    const float4* src = (const float4*)(x + (size_t)t * HDIM + c);
    float4 v0 = src[0], v1 = src[1];
    ushort8 o;
    o[0] = f2bf(v0.x * s); o[1] = f2bf(v0.y * s);
    o[2] = f2bf(v0.z * s); o[3] = f2bf(v0.w * s);
    o[4] = f2bf(v1.x * s); o[5] = f2bf(v1.y * s);
    o[6] = f2bf(v1.z * s); o[7] = f2bf(v1.w * s);
    *(ushort8*)(xs + (size_t)pos * HDIM + c) = o;
}

// ---------------- GEMM1: gate/up + SiLU ----------------------------------------
// 2048 blocks (8 e x 256 n-tiles of 16), 4 waves. C-tile 128x16 (x2 mats).
// BK=256: each weight row staged as ONE contiguous 1KB global_load_lds instr.
// LDS 64 KiB: dbuf x (B1 16K + B3 16K). A (xs, L2-hot) direct to registers.
__global__ void __launch_bounds__(256, 2)
k_moe1(const unsigned short* __restrict__ xs,
       const float* __restrict__ w1,
       const float* __restrict__ w3,
       const int* __restrict__ off,
       unsigned short* __restrict__ hbuf) {
    __shared__ char smem[65536];
    const int NK = HDIM / 256;  // 8

    const int tid = threadIdx.x;
    const int w = tid >> 6, l = tid & 63;
    const int lr = l & 15, hi = l >> 4;
    const int e = blockIdx.x >> 8;
    const int n0 = (blockIdx.x & 255) * 16;
    const int pos_beg = off[e], pos_end = off[e + 1];

    const char* w1b = (const char*)(w1 + (size_t)e * IDIM * HDIM);
    const char* w3b = (const char*)(w3 + (size_t)e * IDIM * HDIM);

    for (int m0 = pos_beg; m0 < pos_end; m0 += 128) {
        const unsigned short* pA[2];
#pragma unroll
        for (int fm = 0; fm < 2; ++fm) {
            int gr = m0 + w * 32 + fm * 16 + lr; if (gr > T_TOK - 1) gr = T_TOK - 1;
            pA[fm] = xs + (size_t)gr * HDIM + hi * 8;
        }

        f32x4 accG[2], accU[2];
#pragma unroll
        for (int i = 0; i < 2; ++i) { accG[i] = (f32x4){0,0,0,0}; accU[i] = (f32x4){0,0,0,0}; }

        auto stage = [&](int buf, int ks) {
#pragma unroll
            for (int j = 0; j < 4; ++j) {
                const int r = w * 4 + j;
                const size_t rb = ((size_t)(n0 + r) * HDIM + ks * 256) * 4;
                const int srcoff = (l ^ (r & 7)) << 4;   // in-chunk swizzle
                gload_lds16(w1b + rb + srcoff, smem + buf * 32768 + r * 1024);
                gload_lds16(w3b + rb + srcoff, smem + buf * 32768 + 16384 + r * 1024);
            }
        };

        stage(0, 0);
#pragma unroll 1
        for (int ks = 0; ks < NK; ++ks) {
            const int cb = ks & 1;
            bf16x8 aC[2][8];
#pragma unroll
            for (int fm = 0; fm < 2; ++fm)
#pragma unroll
                for (int kc = 0; kc < 8; ++kc)
                    aC[fm][kc] = *(const bf16x8*)(pA[fm] + ks * 256 + kc * 32);
            __builtin_amdgcn_sched_barrier(0);
            if (ks + 1 < NK) {
                stage(cb ^ 1, ks + 1);
                asm volatile("s_waitcnt vmcnt(24)" ::: "memory"); // cur-buf stage landed
            } else {
                asm volatile("s_waitcnt vmcnt(16)" ::: "memory");
            }
            __builtin_amdgcn_s_barrier();

            const char* r1 = smem + cb * 32768 + lr * 1024;
            const char* r3 = r1 + 16384;
            const int sw = lr & 7;
#pragma unroll
            for (int kc = 0; kc < 8; ++kc) {
                const int u0 = kc * 8 + hi * 2;
                f32x4 g0 = *(const f32x4*)(r1 + ((u0 ^ sw) << 4));
                f32x4 g1 = *(const f32x4*)(r1 + (((u0 + 1) ^ sw) << 4));
                f32x4 q0 = *(const f32x4*)(r3 + ((u0 ^ sw) << 4));
                f32x4 q1 = *(const f32x4*)(r3 + (((u0 + 1) ^ sw) << 4));
                bf16x8 bg = cvt8(g0, g1);
                bf16x8 bu = cvt8(q0, q1);
#pragma unroll
                for (int fm = 0; fm < 2; ++fm) {
                    accG[fm] = __builtin_amdgcn_mfma_f32_16x16x32_bf16(
                        aC[fm][kc], bg, accG[fm], 0, 0, 0);
                    accU[fm] = __builtin_amdgcn_mfma_f32_16x16x32_bf16(
                        aC[fm][kc], bu, accU[fm], 0, 0, 0);
                }
            }
            asm volatile("s_waitcnt lgkmcnt(0)" ::: "memory");
            __builtin_amdgcn_sched_barrier(0);
            __builtin_amdgcn_s_barrier();
        }

        // epilogue: h = silu(gate) * up -> bf16 (C: col=l&15, row=hi*4+r)
#pragma unroll
        for (int fm = 0; fm < 2; ++fm)
#pragma unroll
            for (int r = 0; r < 4; ++r) {
                const int pos = m0 + w * 32 + fm * 16 + hi * 4 + r;
                if (pos < pos_end) {
                    const float gv = accG[fm][r];
                    const float uv = accU[fm][r];
                    const float hv = gv / (1.f + __expf(-gv)) * uv;
                    hbuf[(size_t)pos * IDIM + n0 + lr] = f2bf(hv);
                }
            }
    }
}

// ---------------- GEMM2: down proj + scatter -----------------------------------
// 1024 blocks (8 e x 128 n-tiles of 16), 4 waves. C-tile 128x16, K=4096.
// LDS 32 KiB: dbuf x B 16K. A (hbuf, L2-hot) direct to registers.
__global__ void __launch_bounds__(256, 3)
k_moe2(const unsigned short* __restrict__ hbuf,
       const float* __restrict__ w2,
       const int* __restrict__ off,
       const int* __restrict__ tok,
       float* __restrict__ out) {
    __shared__ char smem[32768];
    const int NK = IDIM / 256;  // 16

    const int tid = threadIdx.x;
    const int w = tid >> 6, l = tid & 63;
    const int lr = l & 15, hi = l >> 4;
    const int e = blockIdx.x >> 7;
    const int n0 = (blockIdx.x & 127) * 16;
    const int pos_beg = off[e], pos_end = off[e + 1];
    const char* w2b = (const char*)(w2 + (size_t)e * HDIM * IDIM);

    for (int m0 = pos_beg; m0 < pos_end; m0 += 128) {
        const unsigned short* pA[2];
#pragma unroll
        for (int fm = 0; fm < 2; ++fm) {
            int gr = m0 + w * 32 + fm * 16 + lr; if (gr > T_TOK - 1) gr = T_TOK - 1;
            pA[fm] = hbuf + (size_t)gr * IDIM + hi * 8;
        }

        f32x4 acc[2];
        acc[0] = (f32x4){0,0,0,0}; acc[1] = (f32x4){0,0,0,0};

        auto stage = [&](int buf, int ks) {
#pragma unroll
            for (int j = 0; j < 4; ++j) {
                const int r = w * 4 + j;
                const size_t rb = ((size_t)(n0 + r) * IDIM + ks * 256) * 4;
                const int srcoff = (l ^ (r & 7)) << 4;
                gload_lds16(w2b + rb + srcoff, smem + buf * 16384 + r * 1024);
            }
        };

        stage(0, 0);
#pragma unroll 1
        for (int ks = 0; ks < NK; ++ks) {
            const int cb = ks & 1;
            bf16x8 aC[2][8];
#pragma unroll
            for (int fm = 0; fm < 2; ++fm)
#pragma unroll
                for (int kc = 0; kc < 8; ++kc)
                    aC[fm][kc] = *(const bf16x8*)(pA[fm] + ks * 256 + kc * 32);
            __builtin_amdgcn_sched_barrier(0);
            if (ks + 1 < NK) {
                stage(cb ^ 1, ks + 1);
                asm volatile("s_waitcnt vmcnt(20)" ::: "memory");
            } else {
                asm volatile("s_waitcnt vmcnt(16)" ::: "memory");
            }
            __builtin_amdgcn_s_barrier();

            const char* rB = smem + cb * 16384 + lr * 1024;
            const int sw = lr & 7;
#pragma unroll
            for (int kc = 0; kc < 8; ++kc) {
                const int u0 = kc * 8 + hi * 2;
                f32x4 b0 = *(const f32x4*)(rB + ((u0 ^ sw) << 4));
                f32x4 b1 = *(const f32x4*)(rB + (((u0 + 1) ^ sw) << 4));
                bf16x8 bb = cvt8(b0, b1);
#pragma unroll
                for (int fm = 0; fm < 2; ++fm)
                    acc[fm] = __builtin_amdgcn_mfma_f32_16x16x32_bf16(
                        aC[fm][kc], bb, acc[fm], 0, 0, 0);
            }
            asm volatile("s_waitcnt lgkmcnt(0)" ::: "memory");
            __builtin_amdgcn_sched_barrier(0);
            __builtin_amdgcn_s_barrier();
        }

#pragma unroll
        for (int fm = 0; fm < 2; ++fm)
#pragma unroll
            for (int r = 0; r < 4; ++r) {
                const int pos = m0 + w * 32 + fm * 16 + hi * 4 + r;
                if (pos < pos_end) {
                    const int t = tok[pos];
                    out[(size_t)t * HDIM + n0 + lr] = acc[fm][r];
                }
            }
    }
}

extern "C" void kernel_launch(void* const* d_in, const int* in_sizes, int n_in,
                              void* d_out, int out_size, void* d_ws, size_t ws_size,
                              hipStream_t stream) {
    const float* x      = (const float*)d_in[0];
    const float* logits = (const float*)d_in[1];
    const float* w1     = (const float*)d_in[2];
    const float* w3     = (const float*)d_in[3];
    const float* w2     = (const float*)d_in[4];
    float* out = (float*)d_out;

    char* ws = (char*)d_ws;
    int* off   = (int*)ws;                          // 9 ints
    int* tok   = (int*)(ws + 64);                   // 512 ints
    float* scl = (float*)(ws + 64 + 2048);          // 512 floats
    unsigned short* xs   = (unsigned short*)(ws + 8192);                             // 2 MiB
    unsigned short* hbuf = (unsigned short*)(ws + 8192 + (size_t)T_TOK * HDIM * 2);  // 4 MiB

    k_route<<<1, T_TOK, 0, stream>>>(logits, off, tok, scl);
    k_gather<<<T_TOK, 256, 0, stream>>>(x, tok, scl, xs);
    k_moe1<<<NEXP * (IDIM / 16), 256, 0, stream>>>(xs, w1, w3, off, hbuf);
    k_moe2<<<NEXP * (HDIM / 16), 256, 0, stream>>>(hbuf, w2, off, tok, out);
}

// Round 9
// 288.423 us; speedup vs baseline: 1.2089x; 1.0784x over previous
//
#include <hip/hip_runtime.h>

#define T_TOK 512
#define HDIM 2048
#define NEXP 8
#define IDIM 4096

typedef float f32x4 __attribute__((ext_vector_type(4)));
typedef __bf16 bf16x8 __attribute__((ext_vector_type(8)));
typedef unsigned short ushort8 __attribute__((ext_vector_type(8)));

static __device__ __forceinline__ unsigned short f2bf(float f) {
    unsigned int u = __float_as_uint(f);
    u = (u + 0x7fffu + ((u >> 16) & 1u)) >> 16;
    return (unsigned short)u;
}

static __device__ __forceinline__ bf16x8 cvt8(const f32x4 lo, const f32x4 hi) {
    bf16x8 r;
#pragma unroll
    for (int q = 0; q < 4; ++q) { r[q] = (__bf16)lo[q]; r[q + 4] = (__bf16)hi[q]; }
    return r;
}

// async global->LDS, 16 B/lane; LDS dest = wave-uniform base + lane*16,
// global source is PER-LANE (carries the in-row granule swizzle)
static __device__ __forceinline__ void gload_lds16(const void* g, void* l) {
    auto gp = reinterpret_cast<const unsigned int __attribute__((address_space(1)))*>(
        reinterpret_cast<unsigned long long>(g));
    auto lp = reinterpret_cast<unsigned int __attribute__((address_space(3)))*>(
        static_cast<unsigned int>(reinterpret_cast<unsigned long long>(l)));
    __builtin_amdgcn_global_load_lds(gp, lp, 16, 0, 0);
}

// ---------------- routing ------------------------------------------------------
__global__ void k_route(const float* __restrict__ logits,
                        int* __restrict__ off, int* __restrict__ tok,
                        float* __restrict__ scale) {
    __shared__ int cnt[NEXP], cur[NEXP];
    const int t = threadIdx.x;
    if (t < NEXP) cnt[t] = 0;
    __syncthreads();
    float m = logits[t * NEXP];
    int a = 0;
#pragma unroll
    for (int j = 1; j < NEXP; ++j) {
        float v = logits[t * NEXP + j];
        if (v > m) { m = v; a = j; }
    }
    scale[t] = 1.f / (1.f + __expf(-m));
    atomicAdd(&cnt[a], 1);
    __syncthreads();
    if (t == 0) {
        int o = 0;
        for (int e = 0; e < NEXP; ++e) { off[e] = o; cur[e] = o; o += cnt[e]; }
        off[NEXP] = o;
    }
    __syncthreads();
    int r = atomicAdd(&cur[a], 1);
    tok[r] = t;
}

// ---------------- gather + scale + bf16 ---------------------------------------
__global__ void k_gather(const float* __restrict__ x, const int* __restrict__ tok,
                         const float* __restrict__ scale,
                         unsigned short* __restrict__ xs) {
    const int pos = blockIdx.x;
    const int t = tok[pos];
    const float s = scale[t];
    const int c = threadIdx.x * 8;
    const float4* src = (const float4*)(x + (size_t)t * HDIM + c);
    float4 v0 = src[0], v1 = src[1];
    ushort8 o;
    o[0] = f2bf(v0.x * s); o[1] = f2bf(v0.y * s);
    o[2] = f2bf(v0.z * s); o[3] = f2bf(v0.w * s);
    o[4] = f2bf(v1.x * s); o[5] = f2bf(v1.y * s);
    o[6] = f2bf(v1.z * s); o[7] = f2bf(v1.w * s);
    *(ushort8*)(xs + (size_t)pos * HDIM + c) = o;
}

// shared A-frag loader: 2 fm x 4 kc bf16x8 for one BK=128 step
#define LA(dst, ks)                                                          \
    {                                                                        \
        _Pragma("unroll") for (int fm = 0; fm < 2; ++fm)                     \
            _Pragma("unroll") for (int kc = 0; kc < 4; ++kc)                 \
                dst[fm][kc] = *(const bf16x8*)(pA[fm] + (ks) * 128 + kc * 32);\
    }

// ---------------- GEMM1: gate/up + SiLU — depth-3 ring pipeline ----------------
// 2048 blocks (8e x 256 ntiles of 16), 4 waves, C-tile 128x16 (x2 mats), BK=128.
// LDS 48K: 3 bufs x (B1 8K + B3 8K). Two stages (32KB/block) ALWAYS in flight.
__global__ void __launch_bounds__(256, 3)
k_moe1(const unsigned short* __restrict__ xs,
       const float* __restrict__ w1,
       const float* __restrict__ w3,
       const int* __restrict__ off,
       unsigned short* __restrict__ hbuf) {
    __shared__ char smem[49152];
    const int NK = HDIM / 128;  // 16

    const int tid = threadIdx.x;
    const int w = tid >> 6, l = tid & 63;
    const int lr = l & 15, hi = l >> 4;
    const int e = blockIdx.x >> 8;
    const int n0 = (blockIdx.x & 255) * 16;
    const int pos_beg = off[e], pos_end = off[e + 1];

    const char* w1b = (const char*)(w1 + (size_t)e * IDIM * HDIM);
    const char* w3b = (const char*)(w3 + (size_t)e * IDIM * HDIM);

    // staging lane constants: instr q covers rows 2q,2q+1 (512B each)
    const int sg_r  = (w * 2) * 2 + (l >> 5);       // + j*2
    const int sg_pg = l & 31;                        // phys granule in row

    for (int m0 = pos_beg; m0 < pos_end; m0 += 128) {
        const unsigned short* pA[2];
#pragma unroll
        for (int fm = 0; fm < 2; ++fm) {
            int gr = m0 + w * 32 + fm * 16 + lr; if (gr > T_TOK - 1) gr = T_TOK - 1;
            pA[fm] = xs + (size_t)gr * HDIM + hi * 8;
        }

        f32x4 accG[2], accU[2];
#pragma unroll
        for (int i = 0; i < 2; ++i) { accG[i] = (f32x4){0,0,0,0}; accU[i] = (f32x4){0,0,0,0}; }

        auto stage = [&](int buf, int ks) {
#pragma unroll
            for (int j = 0; j < 2; ++j) {
                const int q = w * 2 + j;
                const int r = sg_r + j * 2;
                const size_t so = ((size_t)(n0 + r) * HDIM + ks * 128) * 4 +
                                  ((sg_pg ^ (r & 7)) << 4);
                gload_lds16(w1b + so, smem + buf * 16384 + q * 1024);
                gload_lds16(w3b + so, smem + buf * 16384 + 8192 + q * 1024);
            }
        };

#define CMP1(afrag)                                                          \
    {                                                                        \
        const char* r1 = smem + cc * 16384 + lr * 512;                       \
        const char* r3 = r1 + 8192;                                          \
        _Pragma("unroll") for (int kc = 0; kc < 4; ++kc) {                   \
            const int p0 = ((kc * 8 + hi * 2) ^ (lr & 7)) << 4;              \
            f32x4 g0 = *(const f32x4*)(r1 + p0);                             \
            f32x4 g1 = *(const f32x4*)(r1 + (p0 ^ 16));                      \
            f32x4 q0 = *(const f32x4*)(r3 + p0);                             \
            f32x4 q1 = *(const f32x4*)(r3 + (p0 ^ 16));                      \
            bf16x8 bg = cvt8(g0, g1);                                        \
            bf16x8 bu = cvt8(q0, q1);                                        \
            _Pragma("unroll") for (int fm = 0; fm < 2; ++fm) {               \
                accG[fm] = __builtin_amdgcn_mfma_f32_16x16x32_bf16(          \
                    afrag[fm][kc], bg, accG[fm], 0, 0, 0);                   \
                accU[fm] = __builtin_amdgcn_mfma_f32_16x16x32_bf16(          \
                    afrag[fm][kc], bu, accU[fm], 0, 0, 0);                   \
            }                                                                \
        }                                                                    \
    }

#define BODY1(ks, CUR, NXT)                                                  \
    {                                                                        \
        if ((ks) + 1 < NK) LA(NXT, (ks) + 1)                                 \
        if ((ks) + 2 < NK) stage(cn, (ks) + 2);                              \
        if ((ks) + 2 < NK)      asm volatile("s_waitcnt vmcnt(16)" ::: "memory"); \
        else if ((ks) + 1 < NK) asm volatile("s_waitcnt vmcnt(12)" ::: "memory"); \
        else                    asm volatile("s_waitcnt vmcnt(0)" ::: "memory");  \
        __builtin_amdgcn_s_barrier();                                        \
        CMP1(CUR)                                                            \
        asm volatile("s_waitcnt lgkmcnt(0)" ::: "memory");                   \
        __builtin_amdgcn_sched_barrier(0);                                   \
        __builtin_amdgcn_s_barrier();                                        \
        cc = (cc == 2) ? 0 : cc + 1;                                         \
        cn = (cn == 2) ? 0 : cn + 1;                                         \
    }

        bf16x8 aC[2][4], aN[2][4];
        LA(aC, 0)
        stage(0, 0);
        stage(1, 1);
        int cc = 0, cn = 2;
#pragma unroll 1
        for (int ks = 0; ks < NK; ks += 2) {
            BODY1(ks, aC, aN)
            BODY1(ks + 1, aN, aC)
        }
#undef BODY1
#undef CMP1

        // epilogue: h = silu(gate) * up -> bf16 (C: col=l&15, row=hi*4+r)
#pragma unroll
        for (int fm = 0; fm < 2; ++fm)
#pragma unroll
            for (int r = 0; r < 4; ++r) {
                const int pos = m0 + w * 32 + fm * 16 + hi * 4 + r;
                if (pos < pos_end) {
                    const float gv = accG[fm][r];
                    const float uv = accU[fm][r];
                    const float hv = gv / (1.f + __expf(-gv)) * uv;
                    hbuf[(size_t)pos * IDIM + n0 + lr] = f2bf(hv);
                }
            }
    }
}

// ---------------- GEMM2: down proj + scatter — depth-3 ring pipeline ------------
// 1024 blocks (8e x 128 ntiles of 16), 4 waves, C-tile 128x16, K=4096, BK=128.
// LDS 24K: 3 bufs x 8K.
__global__ void __launch_bounds__(256, 4)
k_moe2(const unsigned short* __restrict__ hbuf,
       const float* __restrict__ w2,
       const int* __restrict__ off,
       const int* __restrict__ tok,
       float* __restrict__ out) {
    __shared__ char smem[24576];
    const int NK = IDIM / 128;  // 32

    const int tid = threadIdx.x;
    const int w = tid >> 6, l = tid & 63;
    const int lr = l & 15, hi = l >> 4;
    const int e = blockIdx.x >> 7;
    const int n0 = (blockIdx.x & 127) * 16;
    const int pos_beg = off[e], pos_end = off[e + 1];
    const char* w2b = (const char*)(w2 + (size_t)e * HDIM * IDIM);

    const int sg_r  = (w * 2) * 2 + (l >> 5);
    const int sg_pg = l & 31;

    for (int m0 = pos_beg; m0 < pos_end; m0 += 128) {
        const unsigned short* pA[2];
#pragma unroll
        for (int fm = 0; fm < 2; ++fm) {
            int gr = m0 + w * 32 + fm * 16 + lr; if (gr > T_TOK - 1) gr = T_TOK - 1;
            pA[fm] = hbuf + (size_t)gr * IDIM + hi * 8;
        }

        f32x4 acc[2];
        acc[0] = (f32x4){0,0,0,0}; acc[1] = (f32x4){0,0,0,0};

        auto stage = [&](int buf, int ks) {
#pragma unroll
            for (int j = 0; j < 2; ++j) {
                const int q = w * 2 + j;
                const int r = sg_r + j * 2;
                const size_t so = ((size_t)(n0 + r) * IDIM + ks * 128) * 4 +
                                  ((sg_pg ^ (r & 7)) << 4);
                gload_lds16(w2b + so, smem + buf * 8192 + q * 1024);
            }
        };

#define CMP2(afrag)                                                          \
    {                                                                        \
        const char* rB = smem + cc * 8192 + lr * 512;                        \
        _Pragma("unroll") for (int kc = 0; kc < 4; ++kc) {                   \
            const int p0 = ((kc * 8 + hi * 2) ^ (lr & 7)) << 4;              \
            f32x4 b0 = *(const f32x4*)(rB + p0);                             \
            f32x4 b1 = *(const f32x4*)(rB + (p0 ^ 16));                      \
            bf16x8 bb = cvt8(b0, b1);                                        \
            _Pragma("unroll") for (int fm = 0; fm < 2; ++fm)                 \
                acc[fm] = __builtin_amdgcn_mfma_f32_16x16x32_bf16(           \
                    afrag[fm][kc], bb, acc[fm], 0, 0, 0);                    \
        }                                                                    \
    }

#define BODY2(ks, CUR, NXT)                                                  \
    {                                                                        \
        if ((ks) + 1 < NK) LA(NXT, (ks) + 1)                                 \
        if ((ks) + 2 < NK) stage(cn, (ks) + 2);                              \
        if ((ks) + 2 < NK)      asm volatile("s_waitcnt vmcnt(12)" ::: "memory"); \
        else if ((ks) + 1 < NK) asm volatile("s_waitcnt vmcnt(10)" ::: "memory"); \
        else                    asm volatile("s_waitcnt vmcnt(0)" ::: "memory");  \
        __builtin_amdgcn_s_barrier();                                        \
        CMP2(CUR)                                                            \
        asm volatile("s_waitcnt lgkmcnt(0)" ::: "memory");                   \
        __builtin_amdgcn_sched_barrier(0);                                   \
        __builtin_amdgcn_s_barrier();                                        \
        cc = (cc == 2) ? 0 : cc + 1;                                         \
        cn = (cn == 2) ? 0 : cn + 1;                                         \
    }

        bf16x8 aC[2][4], aN[2][4];
        LA(aC, 0)
        stage(0, 0);
        stage(1, 1);
        int cc = 0, cn = 2;
#pragma unroll 1
        for (int ks = 0; ks < NK; ks += 2) {
            BODY2(ks, aC, aN)
            BODY2(ks + 1, aN, aC)
        }
#undef BODY2
#undef CMP2

#pragma unroll
        for (int fm = 0; fm < 2; ++fm)
#pragma unroll
            for (int r = 0; r < 4; ++r) {
                const int pos = m0 + w * 32 + fm * 16 + hi * 4 + r;
                if (pos < pos_end) {
                    const int t = tok[pos];
                    out[(size_t)t * HDIM + n0 + lr] = acc[fm][r];
                }
            }
    }
}

extern "C" void kernel_launch(void* const* d_in, const int* in_sizes, int n_in,
                              void* d_out, int out_size, void* d_ws, size_t ws_size,
                              hipStream_t stream) {
    const float* x      = (const float*)d_in[0];
    const float* logits = (const float*)d_in[1];
    const float* w1     = (const float*)d_in[2];
    const float* w3     = (const float*)d_in[3];
    const float* w2     = (const float*)d_in[4];
    float* out = (float*)d_out;

    char* ws = (char*)d_ws;
    int* off   = (int*)ws;                          // 9 ints
    int* tok   = (int*)(ws + 64);                   // 512 ints
    float* scl = (float*)(ws + 64 + 2048);          // 512 floats
    unsigned short* xs   = (unsigned short*)(ws + 8192);                             // 2 MiB
    unsigned short* hbuf = (unsigned short*)(ws + 8192 + (size_t)T_TOK * HDIM * 2);  // 4 MiB

    k_route<<<1, T_TOK, 0, stream>>>(logits, off, tok, scl);
    k_gather<<<T_TOK, 256, 0, stream>>>(x, tok, scl, xs);
    k_moe1<<<NEXP * (IDIM / 16), 256, 0, stream>>>(xs, w1, w3, off, hbuf);
    k_moe2<<<NEXP * (HDIM / 16), 256, 0, stream>>>(hbuf, w2, off, tok, out);
}

// Round 10
// 190.423 us; speedup vs baseline: 1.8310x; 1.5146x over previous
//
#include <hip/hip_runtime.h>

#define T_TOK 512
#define HDIM 2048
#define NEXP 8
#define IDIM 4096

typedef float f32x4 __attribute__((ext_vector_type(4)));
typedef __bf16 bf16x8 __attribute__((ext_vector_type(8)));
typedef unsigned short ushort8 __attribute__((ext_vector_type(8)));

static __device__ __forceinline__ unsigned short f2bf(float f) {
    unsigned int u = __float_as_uint(f);
    u = (u + 0x7fffu + ((u >> 16) & 1u)) >> 16;
    return (unsigned short)u;
}

static __device__ __forceinline__ bf16x8 cvt8(const f32x4 lo, const f32x4 hi) {
    bf16x8 r;
#pragma unroll
    for (int q = 0; q < 4; ++q) { r[q] = (__bf16)lo[q]; r[q + 4] = (__bf16)hi[q]; }
    return r;
}

// async global->LDS, 16 B/lane; LDS dest = wave-uniform base + lane*16,
// global source is PER-LANE (carries the granule swizzle)
static __device__ __forceinline__ void gload_lds16(const void* g, void* l) {
    auto gp = reinterpret_cast<const unsigned int __attribute__((address_space(1)))*>(
        reinterpret_cast<unsigned long long>(g));
    auto lp = reinterpret_cast<unsigned int __attribute__((address_space(3)))*>(
        static_cast<unsigned int>(reinterpret_cast<unsigned long long>(l)));
    __builtin_amdgcn_global_load_lds(gp, lp, 16, 0, 0);
}

// ---------------- routing ------------------------------------------------------
__global__ void k_route(const float* __restrict__ logits,
                        int* __restrict__ off, int* __restrict__ tok,
                        float* __restrict__ scale) {
    __shared__ int cnt[NEXP], cur[NEXP];
    const int t = threadIdx.x;
    if (t < NEXP) cnt[t] = 0;
    __syncthreads();
    float m = logits[t * NEXP];
    int a = 0;
#pragma unroll
    for (int j = 1; j < NEXP; ++j) {
        float v = logits[t * NEXP + j];
        if (v > m) { m = v; a = j; }
    }
    scale[t] = 1.f / (1.f + __expf(-m));
    atomicAdd(&cnt[a], 1);
    __syncthreads();
    if (t == 0) {
        int o = 0;
        for (int e = 0; e < NEXP; ++e) { off[e] = o; cur[e] = o; o += cnt[e]; }
        off[NEXP] = o;
    }
    __syncthreads();
    int r = atomicAdd(&cur[a], 1);
    tok[r] = t;
}

// ---------------- gather + scale + bf16 ---------------------------------------
__global__ void k_gather(const float* __restrict__ x, const int* __restrict__ tok,
                         const float* __restrict__ scale,
                         unsigned short* __restrict__ xs) {
    const int pos = blockIdx.x;
    const int t = tok[pos];
    const float s = scale[t];
    const int c = threadIdx.x * 8;
    const float4* src = (const float4*)(x + (size_t)t * HDIM + c);
    float4 v0 = src[0], v1 = src[1];
    ushort8 o;
    o[0] = f2bf(v0.x * s); o[1] = f2bf(v0.y * s);
    o[2] = f2bf(v0.z * s); o[3] = f2bf(v0.w * s);
    o[4] = f2bf(v1.x * s); o[5] = f2bf(v1.y * s);
    o[6] = f2bf(v1.z * s); o[7] = f2bf(v1.w * s);
    *(ushort8*)(xs + (size_t)pos * HDIM + c) = o;
}

// ---------------- GEMM1: gate/up + SiLU ----------------------------------------
// 512 blocks: expert = bid&7 (-> one expert per XCD), ntile = bid>>3 (64 of BN=64).
// 512 thr = 8 waves (2x4); wave owns 64x16 of the 128x64 C-tile (x2 mats).
// BK=64, single-buffer LDS 48K: A[128][64]bf16 @0, B1[64][64]f32 @16K, B3 @32K.
// Swizzle: 16-B granule XOR (row&7)<<4 on both stage-source and read (rule 21).
__global__ void __launch_bounds__(512, 4)
k_moe1(const unsigned short* __restrict__ xs,
       const float* __restrict__ w1,
       const float* __restrict__ w3,
       const int* __restrict__ off,
       unsigned short* __restrict__ hbuf) {
    __shared__ char smem[49152];

    const int tid = threadIdx.x;
    const int w = tid >> 6, l = tid & 63;
    const int wr = w >> 2, wc = w & 3;
    const int e = blockIdx.x & 7;
    const int n0 = (blockIdx.x >> 3) * 64;
    const int pos_beg = off[e], pos_end = off[e + 1];

    const char* w1b = (const char*)(w1 + (size_t)e * IDIM * HDIM);
    const char* w3b = (const char*)(w3 + (size_t)e * IDIM * HDIM);
    const char* xsb = (const char*)xs;

    const int ia = w * 2;                       // instr ids ia, ia+1
    const int arow_off = l >> 3;                // A: row = i*8 + (l>>3)
    const int asw = ((l & 7) ^ (l >> 3)) << 4;  // A source granule swizzle
    const int brow_off = l >> 4;                // B: row = i*4 + (l>>4)

    for (int m0 = pos_beg; m0 < pos_end; m0 += 128) {
        f32x4 accG[4], accU[4];
#pragma unroll
        for (int i = 0; i < 4; ++i) { accG[i] = (f32x4){0,0,0,0}; accU[i] = (f32x4){0,0,0,0}; }

#pragma unroll 1
        for (int ks = 0; ks < HDIM / 64; ++ks) {
            const int k0 = ks * 64;
            // stage A tile: 16 x 1KB instrs (rows i*8..i*8+7 each)
#pragma unroll
            for (int j = 0; j < 2; ++j) {
                const int i = ia + j;
                int gr = m0 + i * 8 + arow_off; if (gr > T_TOK - 1) gr = T_TOK - 1;
                gload_lds16(xsb + (size_t)gr * (HDIM * 2) + k0 * 2 + asw, smem + i * 1024);
            }
            // stage B tiles: 16 x 1KB instrs each (rows i*4..i*4+3, 256B rows)
#pragma unroll
            for (int j = 0; j < 2; ++j) {
                const int i = ia + j;
                const int r = i * 4 + brow_off;
                const size_t so = (size_t)(n0 + r) * (HDIM * 4) + k0 * 4 +
                                  (((l & 15) << 4) ^ ((r & 7) << 4));
                gload_lds16(w1b + so, smem + 16384 + i * 1024);
                gload_lds16(w3b + so, smem + 32768 + i * 1024);
            }
            __syncthreads();   // drains vmcnt: staged tiles ready

#pragma unroll
            for (int kk = 0; kk < 2; ++kk) {
                bf16x8 a[4];
#pragma unroll
                for (int fm = 0; fm < 4; ++fm) {
                    const int row = wr * 64 + fm * 16 + (l & 15);
                    const int kb = (kk * 64 + ((l >> 4) << 4)) ^ ((l & 7) << 4);
                    a[fm] = *(const bf16x8*)(smem + row * 128 + kb);
                }
                const int rB = wc * 16 + (l & 15);
                const int p0 = (kk * 128 + ((l >> 4) << 5)) ^ ((l & 7) << 4);
                const char* pg = smem + 16384 + rB * 256;
                const char* pu = smem + 32768 + rB * 256;
                f32x4 g0 = *(const f32x4*)(pg + p0);
                f32x4 g1 = *(const f32x4*)(pg + (p0 ^ 16));
                f32x4 u0 = *(const f32x4*)(pu + p0);
                f32x4 u1 = *(const f32x4*)(pu + (p0 ^ 16));
                bf16x8 bg = cvt8(g0, g1);
                bf16x8 bu = cvt8(u0, u1);
#pragma unroll
                for (int fm = 0; fm < 4; ++fm) {
                    accG[fm] = __builtin_amdgcn_mfma_f32_16x16x32_bf16(
                        a[fm], bg, accG[fm], 0, 0, 0);
                    accU[fm] = __builtin_amdgcn_mfma_f32_16x16x32_bf16(
                        a[fm], bu, accU[fm], 0, 0, 0);
                }
            }
            __syncthreads();   // all ds_reads done before next stage overwrites
        }

        // epilogue: h = silu(gate) * up -> bf16  (C: col=l&15, row=(l>>4)*4+r)
#pragma unroll
        for (int fm = 0; fm < 4; ++fm)
#pragma unroll
            for (int r = 0; r < 4; ++r) {
                const int pos = m0 + wr * 64 + fm * 16 + (l >> 4) * 4 + r;
                if (pos < pos_end) {
                    const float gv = accG[fm][r];
                    const float uv = accU[fm][r];
                    const float hv = gv / (1.f + __expf(-gv)) * uv;
                    hbuf[(size_t)pos * IDIM + n0 + wc * 16 + (l & 15)] = f2bf(hv);
                }
            }
    }
}

// ---------------- GEMM2: down proj + scatter -----------------------------------
// 1024 blocks: expert = bid&7, ntile = bid>>3 (128 of BN=16). 256 thr (4 waves),
// C-tile 128x16, K=4096, BK=64. LDS 20K: A[128][64]bf16 @0, B[16][64]f32 @16K.
__global__ void __launch_bounds__(256, 4)
k_moe2(const unsigned short* __restrict__ hbuf,
       const float* __restrict__ w2,
       const int* __restrict__ off,
       const int* __restrict__ tok,
       float* __restrict__ out) {
    __shared__ char smem[20480];

    const int tid = threadIdx.x;
    const int w = tid >> 6, l = tid & 63;
    const int e = blockIdx.x & 7;
    const int n0 = (blockIdx.x >> 3) * 16;
    const int pos_beg = off[e], pos_end = off[e + 1];
    const char* w2b = (const char*)(w2 + (size_t)e * HDIM * IDIM);
    const char* hb  = (const char*)hbuf;

    const int ia = w * 4;                       // A instrs ia..ia+3
    const int arow_off = l >> 3;
    const int asw = ((l & 7) ^ (l >> 3)) << 4;
    const int brow_off = l >> 4;                // B instr w: rows w*4..w*4+3

    for (int m0 = pos_beg; m0 < pos_end; m0 += 128) {
        f32x4 acc[2];
        acc[0] = (f32x4){0,0,0,0}; acc[1] = (f32x4){0,0,0,0};

#pragma unroll 1
        for (int ks = 0; ks < IDIM / 64; ++ks) {
            const int k0 = ks * 64;
#pragma unroll
            for (int j = 0; j < 4; ++j) {
                const int i = ia + j;
                int gr = m0 + i * 8 + arow_off; if (gr > T_TOK - 1) gr = T_TOK - 1;
                gload_lds16(hb + (size_t)gr * (IDIM * 2) + k0 * 2 + asw, smem + i * 1024);
            }
            {
                const int r = w * 4 + brow_off;
                const size_t so = (size_t)(n0 + r) * (IDIM * 4) + k0 * 4 +
                                  (((l & 15) << 4) ^ ((r & 7) << 4));
                gload_lds16(w2b + so, smem + 16384 + w * 1024);
            }
            __syncthreads();

#pragma unroll
            for (int kk = 0; kk < 2; ++kk) {
                const int rB = l & 15;
                const int p0 = (kk * 128 + ((l >> 4) << 5)) ^ ((l & 7) << 4);
                const char* pb = smem + 16384 + rB * 256;
                f32x4 b0 = *(const f32x4*)(pb + p0);
                f32x4 b1 = *(const f32x4*)(pb + (p0 ^ 16));
                bf16x8 bb = cvt8(b0, b1);
#pragma unroll
                for (int fm = 0; fm < 2; ++fm) {
                    const int row = w * 32 + fm * 16 + (l & 15);
                    const int kb = (kk * 64 + ((l >> 4) << 4)) ^ ((l & 7) << 4);
                    bf16x8 a = *(const bf16x8*)(smem + row * 128 + kb);
                    acc[fm] = __builtin_amdgcn_mfma_f32_16x16x32_bf16(a, bb, acc[fm], 0, 0, 0);
                }
            }
            __syncthreads();
        }

#pragma unroll
        for (int fm = 0; fm < 2; ++fm)
#pragma unroll
            for (int r = 0; r < 4; ++r) {
                const int pos = m0 + w * 32 + fm * 16 + (l >> 4) * 4 + r;
                if (pos < pos_end) {
                    const int t = tok[pos];
                    out[(size_t)t * HDIM + n0 + (l & 15)] = acc[fm][r];
                }
            }
    }
}

extern "C" void kernel_launch(void* const* d_in, const int* in_sizes, int n_in,
                              void* d_out, int out_size, void* d_ws, size_t ws_size,
                              hipStream_t stream) {
    const float* x      = (const float*)d_in[0];
    const float* logits = (const float*)d_in[1];
    const float* w1     = (const float*)d_in[2];
    const float* w3     = (const float*)d_in[3];
    const float* w2     = (const float*)d_in[4];
    float* out = (float*)d_out;

    char* ws = (char*)d_ws;
    int* off   = (int*)ws;                          // 9 ints
    int* tok   = (int*)(ws + 64);                   // 512 ints
    float* scl = (float*)(ws + 64 + 2048);          // 512 floats
    unsigned short* xs   = (unsigned short*)(ws + 8192);                             // 2 MiB
    unsigned short* hbuf = (unsigned short*)(ws + 8192 + (size_t)T_TOK * HDIM * 2);  // 4 MiB

    k_route<<<1, T_TOK, 0, stream>>>(logits, off, tok, scl);
    k_gather<<<T_TOK, 256, 0, stream>>>(x, tok, scl, xs);
    k_moe1<<<NEXP * (IDIM / 64), 512, 0, stream>>>(xs, w1, w3, off, hbuf);
    k_moe2<<<NEXP * (HDIM / 16), 256, 0, stream>>>(hbuf, w2, off, tok, out);
}